// Round 1
// baseline (288.113 us; speedup 1.0000x reference)
//
#include <hip/hip_runtime.h>
#include <math.h>

#define AA   64    // batch
#define SEQ  256   // per-path length
#define DIM  8     // feature dim
#define LL   511   // number of increments (2*SEQ - 1)
#define NP   512   // K-grid side (LL + 1)

__global__ void zero_out_kernel(float* out) { out[0] = 0.0f; }

// One block per batch element. 512 threads. Anti-diagonal wavefront sweep of
// the 512x512 Goursat grid with 3 rotating LDS diagonal buffers.
__global__ __launch_bounds__(NP) void sig_solve_kernel(
        const float* __restrict__ X, const float* __restrict__ Y,
        float* __restrict__ out) {
    const int a = blockIdx.x;
    const int t = threadIdx.x;

    __shared__ __align__(16) float zbuf[NP][DIM];   // Z = [X; flip(Y)]
    __shared__ __align__(16) float dzb[LL][DIM];    // increments
    __shared__ float diag[3][NP];                   // rotating anti-diagonals

    // ---- stage Z into LDS (coalesced float4 loads) ----
    {
        const float* src = (t < SEQ) ? (X + ((size_t)a * SEQ + t) * DIM)
                                     : (Y + ((size_t)a * SEQ + (LL - t)) * DIM);
        float4 v0 = reinterpret_cast<const float4*>(src)[0];
        float4 v1 = reinterpret_cast<const float4*>(src)[1];
        *reinterpret_cast<float4*>(&zbuf[t][0]) = v0;
        *reinterpret_cast<float4*>(&zbuf[t][4]) = v1;
    }
    __syncthreads();

    // ---- dz[i] = Z[i+1] - Z[i] ----
    if (t < LL) {
        #pragma unroll
        for (int d = 0; d < DIM; ++d)
            dzb[t][d] = zbuf[t + 1][d] - zbuf[t][d];
    }
    if (t == 0) { diag[0][0] = 1.0f; diag[1][0] = 1.0f; diag[1][1] = 1.0f; }
    __syncthreads();

    // thread t owns grid row r = t; its fixed dz row is i = t-1
    float row[DIM];
    if (t >= 1) {
        float4 r0 = *reinterpret_cast<const float4*>(&dzb[t - 1][0]);
        float4 r1 = *reinterpret_cast<const float4*>(&dzb[t - 1][4]);
        row[0] = r0.x; row[1] = r0.y; row[2] = r0.z; row[3] = r0.w;
        row[4] = r1.x; row[5] = r1.y; row[6] = r1.z; row[7] = r1.w;
    }

    // ---- wavefront sweep: s = r + c, s in [2, 2*LL] ----
    for (int s = 2; s <= 2 * LL; ++s) {
        float* cur        = diag[s % 3];
        const float* p1   = diag[(s + 2) % 3];  // (s-1) % 3
        const float* p2   = diag[(s + 1) % 3];  // (s-2) % 3
        const int rlo = (s - LL) > 1 ? (s - LL) : 1;
        const int rhi = (s - 1) < LL ? (s - 1) : LL;

        if (t >= rlo && t <= rhi) {
            const int j = s - t - 1;                     // dz column index
            const float4 c0 = *reinterpret_cast<const float4*>(&dzb[j][0]);
            const float4 c1 = *reinterpret_cast<const float4*>(&dzb[j][4]);
            float inc = row[0] * c0.x + row[1] * c0.y + row[2] * c0.z + row[3] * c0.w
                      + row[4] * c1.x + row[5] * c1.y + row[6] * c1.z + row[7] * c1.w;
            // K[r][c] = K[r][c-1] + K[r-1][c] + K[r-1][c-1] * (inc - 1)
            cur[t] = p1[t] + p1[t - 1] + p2[t - 1] * (inc - 1.0f);
        }
        if (s <= LL) {  // grid boundaries K[0][s] = K[s][0] = 1
            if (t == 0) cur[0] = 1.0f;
            if (t == s) cur[s] = 1.0f;
        }
        __syncthreads();
    }

    if (t == 0) {
        float k = diag[(2 * LL) % 3][LL];   // K[511][511]
        atomicAdd(out, sqrtf(k - 1.0f) * (1.0f / (float)AA));
    }
}

extern "C" void kernel_launch(void* const* d_in, const int* in_sizes, int n_in,
                              void* d_out, int out_size, void* d_ws, size_t ws_size,
                              hipStream_t stream) {
    const float* X = (const float*)d_in[0];
    const float* Y = (const float*)d_in[1];
    float* out = (float*)d_out;

    zero_out_kernel<<<1, 1, 0, stream>>>(out);
    sig_solve_kernel<<<AA, NP, 0, stream>>>(X, Y, out);
}

// Round 2
// 189.637 us; speedup vs baseline: 1.5193x; 1.5193x over previous
//
#include <hip/hip_runtime.h>
#include <math.h>

#define AA    64    // batch
#define SEQ   256   // per-path length
#define LL    511   // number of increments
#define NPTS  512   // Z length / padded dz rows (dz[511] = 0)
#define NSTEPS (LL + 63)  // 574 skewed wavefront steps

typedef float v2f __attribute__((ext_vector_type(2)));

__global__ void zero_out_kernel(float* out) { out[0] = 0.0f; }

// One WAVE per batch element; no __syncthreads in the sweep. Lane t owns grid
// rows 8t+1..8t+8 (dz rows 8t..8t+7 in registers). Skewed column sweep:
// lane t handles column c = s - t at step s; cross-lane dependency is a
// single __shfl_up of the lane's bottom-row value.
__global__ __launch_bounds__(64) void sig_solve_kernel(
        const float* __restrict__ X, const float* __restrict__ Y,
        float* __restrict__ out) {
    const int a = blockIdx.x;
    const int t = threadIdx.x;   // 0..63

    __shared__ __align__(16) float zbuf[NPTS][8];  // Z = [X; flip(Y)]
    __shared__ v2f dzp[4][NPTS];  // dzp[p][j] = {dz[j][2p], dz[j][2p+1]}, col 511 = 0

    // ---- stage Z (coalesced float4) ----
    for (int p = t; p < NPTS; p += 64) {
        const float* src = (p < SEQ) ? (X + ((size_t)a * SEQ + p) * 8)
                                     : (Y + ((size_t)a * SEQ + (LL - p)) * 8);
        float4 v0 = reinterpret_cast<const float4*>(src)[0];
        float4 v1 = reinterpret_cast<const float4*>(src)[1];
        *reinterpret_cast<float4*>(&zbuf[p][0]) = v0;
        *reinterpret_cast<float4*>(&zbuf[p][4]) = v1;
    }
    __syncthreads();

    // ---- dz pairs into LDS (transposed-by-pair: lane stride 8B = conflict-free) ----
    for (int i = t; i < NPTS; i += 64) {
        #pragma unroll
        for (int p = 0; p < 4; ++p) {
            v2f d;
            if (i < LL) {
                d.x = zbuf[i + 1][2 * p]     - zbuf[i][2 * p];
                d.y = zbuf[i + 1][2 * p + 1] - zbuf[i][2 * p + 1];
            } else {
                d.x = 0.0f; d.y = 0.0f;
            }
            dzp[p][i] = d;
        }
    }
    __syncthreads();

    // ---- this lane's 8 dz rows into registers ----
    v2f rowdz[8][4];
    #pragma unroll
    for (int k = 0; k < 8; ++k) {
        const int r = 8 * t + k;
        #pragma unroll
        for (int p = 0; p < 4; ++p) {
            v2f d;
            if (r < LL) {
                d.x = zbuf[r + 1][2 * p]     - zbuf[r][2 * p];
                d.y = zbuf[r + 1][2 * p + 1] - zbuf[r][2 * p + 1];
            } else {
                d.x = 0.0f; d.y = 0.0f;
            }
            rowdz[k][p] = d;
        }
    }

    float L[8];                    // left column values K[row][c-1]
    #pragma unroll
    for (int k = 0; k < 8; ++k) L[k] = 1.0f;
    float bottom  = 1.0f;          // K[8t+8][c] (this lane's bottom row)
    float nb_prev = 1.0f;          // neighbor bottom at col c-1 (diag for top row)

    // prefetch column dz for step s=1 (j = -t clamped; only lane 0 needs it)
    v2f cdn0, cdn1, cdn2, cdn3;
    {
        int j = -t; j = j < 0 ? 0 : j;
        cdn0 = dzp[0][j]; cdn1 = dzp[1][j]; cdn2 = dzp[2][j]; cdn3 = dzp[3][j];
    }

    for (int s = 1; s <= NSTEPS; ++s) {
        float nb_cur = __shfl_up(bottom, 1, 64);
        if (t == 0) nb_cur = 1.0f;           // K[0][*] = 1 boundary

        const v2f cd0 = cdn0, cd1 = cdn1, cd2 = cdn2, cd3 = cdn3;
        // prefetch next step's column (hidden under the 8 dot products)
        int jn = s - t; jn = jn < 0 ? 0 : (jn > LL ? LL : jn);
        cdn0 = dzp[0][jn]; cdn1 = dzp[1][jn]; cdn2 = dzp[2][jn]; cdn3 = dzp[3][jn];

        const int c = s - t;
        if (c >= 1 && c <= LL) {
            float up = nb_cur, diag = nb_prev;
            #pragma unroll
            for (int k = 0; k < 8; ++k) {
                v2f acc = rowdz[k][0] * cd0;
                acc += rowdz[k][1] * cd1;
                acc += rowdz[k][2] * cd2;
                acc += rowdz[k][3] * cd3;
                const float inc = acc.x + acc.y;
                // K[r][c] = K[r][c-1] + K[r-1][c] + K[r-1][c-1]*(inc-1)
                const float nv = fmaf(diag, inc - 1.0f, L[k]) + up;
                diag = L[k];
                up   = nv;
                L[k] = nv;
            }
            bottom = L[7];
        }
        nb_prev = nb_cur;
    }

    // K[511][511] lives in lane 63, row 511 = 8*63 + 6 + 1 -> L[6]
    if (t == 63) {
        atomicAdd(out, sqrtf(L[6] - 1.0f) * (1.0f / (float)AA));
    }
}

extern "C" void kernel_launch(void* const* d_in, const int* in_sizes, int n_in,
                              void* d_out, int out_size, void* d_ws, size_t ws_size,
                              hipStream_t stream) {
    const float* X = (const float*)d_in[0];
    const float* Y = (const float*)d_in[1];
    float* out = (float*)d_out;

    zero_out_kernel<<<1, 1, 0, stream>>>(out);
    sig_solve_kernel<<<AA, 64, 0, stream>>>(X, Y, out);
}

// Round 3
// 180.809 us; speedup vs baseline: 1.5935x; 1.0488x over previous
//
#include <hip/hip_runtime.h>
#include <math.h>

#define AA    64    // batch
#define SEQ   256   // per-path length
#define LL    511   // number of increments
#define NPTS  512   // Z length / padded dz rows (dz[511] = 0)
#define NSTEPS (LL + 63)  // 574 skewed wavefront steps

typedef float v2f __attribute__((ext_vector_type(2)));

__global__ void zero_out_kernel(float* out) { out[0] = 0.0f; }

// Lane-shift-by-1 across the full 64-lane wave via DPP wave_shr:1 (0x138).
// Pure VALU (~4-8 cy) vs ds_bpermute (~120 cy). Lane 0 receives `fill`.
__device__ __forceinline__ float wave_shr1(float x, float fill) {
    int r = __builtin_amdgcn_update_dpp(__float_as_int(fill), __float_as_int(x),
                                        0x138, 0xF, 0xF, false);
    return __int_as_float(r);
}

// One WAVE per batch element; no barriers, no LDS on the critical path.
// Lane t owns grid rows 8t+1..8t+8 (dz rows 8t..8t+7 in registers). Skewed
// column sweep: lane t handles column c = s - t at step s; the cross-lane
// dependency (neighbor's bottom row) moves via DPP wave_shr:1.
__global__ __launch_bounds__(64) void sig_solve_kernel(
        const float* __restrict__ X, const float* __restrict__ Y,
        float* __restrict__ out) {
    const int a = blockIdx.x;
    const int t = threadIdx.x;   // 0..63

    __shared__ __align__(16) float zbuf[NPTS][8];  // Z = [X; flip(Y)]
    __shared__ v2f dzp[4][NPTS];  // dzp[p][j] = {dz[j][2p], dz[j][2p+1]}, col 511 = 0

    // ---- stage Z (coalesced float4) ----
    for (int p = t; p < NPTS; p += 64) {
        const float* src = (p < SEQ) ? (X + ((size_t)a * SEQ + p) * 8)
                                     : (Y + ((size_t)a * SEQ + (LL - p)) * 8);
        float4 v0 = reinterpret_cast<const float4*>(src)[0];
        float4 v1 = reinterpret_cast<const float4*>(src)[1];
        *reinterpret_cast<float4*>(&zbuf[p][0]) = v0;
        *reinterpret_cast<float4*>(&zbuf[p][4]) = v1;
    }
    __syncthreads();

    // ---- dz pairs into LDS (lane stride 8B = 2-way bank alias = free) ----
    for (int i = t; i < NPTS; i += 64) {
        #pragma unroll
        for (int p = 0; p < 4; ++p) {
            v2f d;
            if (i < LL) {
                d.x = zbuf[i + 1][2 * p]     - zbuf[i][2 * p];
                d.y = zbuf[i + 1][2 * p + 1] - zbuf[i][2 * p + 1];
            } else {
                d.x = 0.0f; d.y = 0.0f;
            }
            dzp[p][i] = d;
        }
    }
    __syncthreads();

    // ---- this lane's 8 dz rows into registers ----
    v2f rowdz[8][4];
    #pragma unroll
    for (int k = 0; k < 8; ++k) {
        const int r = 8 * t + k;
        #pragma unroll
        for (int p = 0; p < 4; ++p) {
            v2f d;
            if (r < LL) {
                d.x = zbuf[r + 1][2 * p]     - zbuf[r][2 * p];
                d.y = zbuf[r + 1][2 * p + 1] - zbuf[r][2 * p + 1];
            } else {
                d.x = 0.0f; d.y = 0.0f;
            }
            rowdz[k][p] = d;
        }
    }

    float L[8];                    // left column values K[row][c-1]
    #pragma unroll
    for (int k = 0; k < 8; ++k) L[k] = 1.0f;
    float bottom  = 1.0f;          // K[8t+8][c] (this lane's bottom row)
    float nb_prev = 1.0f;          // neighbor bottom at col c-1 (diag for top row)

    // prefetch column dz for step s=1 (j = c-1 = -t, clamped; lane 0 real)
    v2f cdn0, cdn1, cdn2, cdn3;
    {
        int j = -t; j = j < 0 ? 0 : j;
        cdn0 = dzp[0][j]; cdn1 = dzp[1][j]; cdn2 = dzp[2][j]; cdn3 = dzp[3][j];
    }

    for (int s = 1; s <= NSTEPS; ++s) {
        const float nb_cur = wave_shr1(bottom, 1.0f);   // K[8t][c], lane0 -> 1.0

        const v2f cd0 = cdn0, cd1 = cdn1, cd2 = cdn2, cd3 = cdn3;
        // prefetch next step's column dz (wait hides under the 32 FMAs below)
        int jn = s - t; jn = jn < 0 ? 0 : (jn > LL ? LL : jn);
        cdn0 = dzp[0][jn]; cdn1 = dzp[1][jn]; cdn2 = dzp[2][jn]; cdn3 = dzp[3][jn];

        const int c = s - t;
        if ((unsigned)(c - 1) < (unsigned)LL) {
            float up = nb_cur, diag = nb_prev;
            #pragma unroll
            for (int k = 0; k < 8; ++k) {
                v2f acc = {-0.5f, -0.5f};               // folds the (inc - 1)
                acc += rowdz[k][0] * cd0;
                acc += rowdz[k][1] * cd1;
                acc += rowdz[k][2] * cd2;
                acc += rowdz[k][3] * cd3;
                const float incm1 = acc.x + acc.y;       // = <dz_r, dz_c> - 1
                // K[r][c] = K[r][c-1] + K[r-1][c] + K[r-1][c-1]*(inc-1)
                // fma is off the serial chain (diag, L[k] are step-start values);
                // only the "+ up" accumulation chains (8 dependent adds).
                const float nv = fmaf(diag, incm1, L[k]) + up;
                diag = L[k];
                up   = nv;
                L[k] = nv;
            }
            bottom = L[7];
        }
        nb_prev = nb_cur;
    }

    // K[511][511] lives in lane 63: row 511 = 8*63 + 6 + 1 -> L[6]
    if (t == 63) {
        atomicAdd(out, sqrtf(L[6] - 1.0f) * (1.0f / (float)AA));
    }
}

extern "C" void kernel_launch(void* const* d_in, const int* in_sizes, int n_in,
                              void* d_out, int out_size, void* d_ws, size_t ws_size,
                              hipStream_t stream) {
    const float* X = (const float*)d_in[0];
    const float* Y = (const float*)d_in[1];
    float* out = (float*)d_out;

    zero_out_kernel<<<1, 1, 0, stream>>>(out);
    sig_solve_kernel<<<AA, 64, 0, stream>>>(X, Y, out);
}

// Round 4
// 173.921 us; speedup vs baseline: 1.6566x; 1.0396x over previous
//
#include <hip/hip_runtime.h>
#include <math.h>

#define AA    64    // batch
#define SEQ   256   // per-path length
#define LL    511   // number of increments
#define NPTS  512   // padded dz rows (dz[511] = 0)
#define NITER 319   // 256 column-pair iterations + 63 skew

typedef float v2f __attribute__((ext_vector_type(2)));
typedef float v4f __attribute__((ext_vector_type(4)));

__global__ void zero_out_kernel(float* out) { out[0] = 0.0f; }

// Full-wave lane shift by 1 (DPP wave_shr:1, ctrl 0x138). Lane 0 <- `fill`'s
// lane-0 value (bound_ctrl=false keeps `old` where no source lane exists).
__device__ __forceinline__ float wave_shr1(float x, float fill) {
    int r = __builtin_amdgcn_update_dpp(__float_as_int(fill), __float_as_int(x),
                                        0x138, 0xF, 0xF, false);
    return __int_as_float(r);
}
__device__ __forceinline__ v2f wave_shr1_v2(v2f x, v2f fill) {
    v2f r;
    r.x = wave_shr1(x.x, fill.x);
    r.y = wave_shr1(x.y, fill.y);
    return r;
}

// One WAVE per batch element, no barriers in the sweep. Lane t owns grid rows
// 8t+1..8t+8 (dz rows in registers). W=2 columns per iteration, skewed: lane
// t handles columns 2(m-t)+1, 2(m-t)+2 at iteration m. Cross-lane traffic
// (neighbor bottom row + column dz pass-along) is pure DPP; the only
// steady-state LDS access is ONE uniform broadcast 64B read per iteration
// (next column pair for lane 0), consumed a full iteration later.
__global__ __launch_bounds__(64) void sig_solve_kernel(
        const float* __restrict__ X, const float* __restrict__ Y,
        float* __restrict__ out) {
    const int a = blockIdx.x;
    const int t = threadIdx.x;   // 0..63

    __shared__ __align__(16) float zbuf[NPTS][8];  // Z = [X; flip(Y)]
    __shared__ __align__(16) v2f  dzc[NPTS][4];    // dz by column, pair-packed

    // ---- stage Z (coalesced float4) ----
    for (int p = t; p < NPTS; p += 64) {
        const float* src = (p < SEQ) ? (X + ((size_t)a * SEQ + p) * 8)
                                     : (Y + ((size_t)a * SEQ + (LL - p)) * 8);
        float4 v0 = reinterpret_cast<const float4*>(src)[0];
        float4 v1 = reinterpret_cast<const float4*>(src)[1];
        *reinterpret_cast<float4*>(&zbuf[p][0]) = v0;
        *reinterpret_cast<float4*>(&zbuf[p][4]) = v1;
    }
    __syncthreads();

    // ---- dz columns into LDS (row 511 zero-padded) ----
    for (int i = t; i < NPTS; i += 64) {
        #pragma unroll
        for (int p = 0; p < 4; ++p) {
            v2f d;
            if (i < LL) {
                d.x = zbuf[i + 1][2 * p]     - zbuf[i][2 * p];
                d.y = zbuf[i + 1][2 * p + 1] - zbuf[i][2 * p + 1];
            } else {
                d.x = 0.0f; d.y = 0.0f;
            }
            dzc[i][p] = d;
        }
    }
    __syncthreads();

    // ---- this lane's 8 dz rows into registers ----
    v2f rowdz[8][4];
    #pragma unroll
    for (int k = 0; k < 8; ++k) {
        const int r = 8 * t + k;
        #pragma unroll
        for (int p = 0; p < 4; ++p) {
            v2f d;
            if (r < LL) {
                d.x = zbuf[r + 1][2 * p]     - zbuf[r][2 * p];
                d.y = zbuf[r + 1][2 * p + 1] - zbuf[r][2 * p + 1];
            } else {
                d.x = 0.0f; d.y = 0.0f;
            }
            rowdz[k][p] = d;
        }
    }

    float L[8];                    // K[row][current col] running values
    #pragma unroll
    for (int k = 0; k < 8; ++k) L[k] = 1.0f;   // column-0 boundary
    float bot0 = 1.0f, bot1 = 1.0f;            // bottom row after col0/col1
    float nb_prev = 1.0f;                      // neighbor bottom, one col back

    // column-dz registers: ca = this lane's current pair (via DPP chain),
    // cb = uniform broadcast of the pair lane 0 needs NEXT iteration.
    v2f ca[2][4], cb[2][4];
    {
        // cb = columns {0,1}; ca initial value irrelevant (replaced via shift)
        union { v4f q; v2f h[2]; } u0, u1, u2, u3;
        u0.q = *reinterpret_cast<const v4f*>(&dzc[0][0]);
        u1.q = *reinterpret_cast<const v4f*>(&dzc[0][2]);
        u2.q = *reinterpret_cast<const v4f*>(&dzc[1][0]);
        u3.q = *reinterpret_cast<const v4f*>(&dzc[1][2]);
        cb[0][0] = u0.h[0]; cb[0][1] = u0.h[1]; cb[0][2] = u1.h[0]; cb[0][3] = u1.h[1];
        cb[1][0] = u2.h[0]; cb[1][1] = u2.h[1]; cb[1][2] = u3.h[0]; cb[1][3] = u3.h[1];
        #pragma unroll
        for (int w = 0; w < 2; ++w)
            #pragma unroll
            for (int p = 0; p < 4; ++p) ca[w][p] = cb[w][p];
    }

    for (int m = 0; m < NITER; ++m) {
        // neighbor bottoms for our two columns (lane 0 -> boundary 1.0)
        const float sb0 = wave_shr1(bot0, 1.0f);
        const float sb1 = wave_shr1(bot1, 1.0f);
        // column pass-along: lane t takes lane t-1's pair; lane 0 takes cb
        #pragma unroll
        for (int w = 0; w < 2; ++w)
            #pragma unroll
            for (int p = 0; p < 4; ++p) ca[w][p] = wave_shr1_v2(ca[w][p], cb[w][p]);

        // issue next uniform broadcast read (used next iteration -> full cover)
        {
            int jr = 2 * m + 2; jr = jr > 510 ? 510 : jr;
            union { v4f q; v2f h[2]; } u0, u1, u2, u3;
            u0.q = *reinterpret_cast<const v4f*>(&dzc[jr][0]);
            u1.q = *reinterpret_cast<const v4f*>(&dzc[jr][2]);
            u2.q = *reinterpret_cast<const v4f*>(&dzc[jr + 1][0]);
            u3.q = *reinterpret_cast<const v4f*>(&dzc[jr + 1][2]);
            cb[0][0] = u0.h[0]; cb[0][1] = u0.h[1]; cb[0][2] = u1.h[0]; cb[0][3] = u1.h[1];
            cb[1][0] = u2.h[0]; cb[1][1] = u2.h[1]; cb[1][2] = u3.h[0]; cb[1][3] = u3.h[1];
        }

        const int um = m - t;
        const bool valid0 = (unsigned)um < 256u;   // col c0 = 2(m-t)+1 in range
        const bool valid1 = (unsigned)um < 255u;   // col c1 = c0+1     in range

        // ---- column c0: up = sb0, diag chain starts at nb_prev ----
        {
            float up = sb0, diag = nb_prev;
            #pragma unroll
            for (int k = 0; k < 8; ++k) {
                v2f acc = {-0.5f, -0.5f};
                acc += rowdz[k][0] * ca[0][0];
                acc += rowdz[k][1] * ca[0][1];
                acc += rowdz[k][2] * ca[0][2];
                acc += rowdz[k][3] * ca[0][3];
                const float incm1 = acc.x + acc.y;
                const float nv = fmaf(diag, incm1, L[k]) + up;
                diag = L[k];
                L[k] = valid0 ? nv : L[k];
                up = nv;
            }
            bot0 = L[7];
        }
        // ---- column c1: up = sb1, diag chain starts at sb0 ----
        {
            float up = sb1, diag = sb0;
            #pragma unroll
            for (int k = 0; k < 8; ++k) {
                v2f acc = {-0.5f, -0.5f};
                acc += rowdz[k][0] * ca[1][0];
                acc += rowdz[k][1] * ca[1][1];
                acc += rowdz[k][2] * ca[1][2];
                acc += rowdz[k][3] * ca[1][3];
                const float incm1 = acc.x + acc.y;
                const float nv = fmaf(diag, incm1, L[k]) + up;
                diag = L[k];
                L[k] = valid1 ? nv : L[k];
                up = nv;
            }
            bot1 = L[7];
        }
        nb_prev = sb1;
    }

    // K[511][511]: lane 63, row 511 = 8*63 + 6 + 1 -> L[6]
    if (t == 63) {
        atomicAdd(out, sqrtf(L[6] - 1.0f) * (1.0f / (float)AA));
    }
}

extern "C" void kernel_launch(void* const* d_in, const int* in_sizes, int n_in,
                              void* d_out, int out_size, void* d_ws, size_t ws_size,
                              hipStream_t stream) {
    const float* X = (const float*)d_in[0];
    const float* Y = (const float*)d_in[1];
    float* out = (float*)d_out;

    zero_out_kernel<<<1, 1, 0, stream>>>(out);
    sig_solve_kernel<<<AA, 64, 0, stream>>>(X, Y, out);
}

// Round 6
// 165.863 us; speedup vs baseline: 1.7371x; 1.0486x over previous
//
#include <hip/hip_runtime.h>
#include <math.h>

#define AA    64    // batch
#define SEQ   256   // per-path length
#define LL    511   // number of increments
#define NPTS  512   // padded dz rows
#define MPAD  320   // padded sweep iterations (319 real: 256 pairs + 63 skew)
#define MCH   16    // m-values per gram2 block
#define GBY   (MPAD / MCH)   // 20

typedef float v2f __attribute__((ext_vector_type(2)));
typedef float v4f __attribute__((ext_vector_type(4)));

__global__ void zero_out_kernel(float* out) { out[0] = 0.0f; }

// Full-wave lane shift by 1 (DPP wave_shr:1, ctrl 0x138). Lane 0 <- `fill`.
__device__ __forceinline__ float wave_shr1(float x, float fill) {
    int r = __builtin_amdgcn_update_dpp(__float_as_int(fill), __float_as_int(x),
                                        0x138, 0xF, 0xF, false);
    return __int_as_float(r);
}
__device__ __forceinline__ v2f wave_shr1_v2(v2f x, v2f fill) {
    v2f r;
    r.x = wave_shr1(x.x, fill.x);
    r.y = wave_shr1(x.y, fill.y);
    return r;
}

// Z point p (0..511) of batch a: X rows then flipped Y rows.
__device__ __forceinline__ const float* zptr(const float* __restrict__ X,
                                             const float* __restrict__ Y,
                                             int a, int p) {
    return (p < SEQ) ? (X + ((size_t)a * SEQ + p) * 8)
                     : (Y + ((size_t)a * SEQ + (LL - p)) * 8);
}
__device__ __forceinline__ void zload(const float* p, v2f z[4]) {
    float4 u = reinterpret_cast<const float4*>(p)[0];
    float4 v = reinterpret_cast<const float4*>(p)[1];
    z[0].x = u.x; z[0].y = u.y; z[1].x = u.z; z[1].y = u.w;
    z[2].x = v.x; z[2].y = v.y; z[3].x = v.z; z[3].y = v.w;
}

// ---------------- phase 1: Gram values in sweep read-order -------------------
// E[a][m][t][w*8+k] = <dz[8t+k], dz[2(m-t)+w]> - 1, 0 when invalid.
// Trivially indexed: one thread per (m, t) pair (4 per thread), all data read
// straight from global (2 MB inputs stay L2/L3-resident). No LDS, no syncs.
__global__ __launch_bounds__(256) void gram2_kernel(
        const float* __restrict__ X, const float* __restrict__ Y,
        float* __restrict__ E) {
    const int a  = blockIdx.x;
    const int m0 = blockIdx.y * MCH;
    const int t  = threadIdx.x & 63;
    const int mg = threadIdx.x >> 6;   // 0..3

    // this thread's 8 dz rows: dz[8t+k] = Z[8t+k+1] - Z[8t+k]; dz[511] = 0
    v2f rowdz[8][4];
    {
        v2f zp[4], zn[4];
        zload(zptr(X, Y, a, 8 * t), zp);
        #pragma unroll
        for (int k = 0; k < 8; ++k) {
            const int r = 8 * t + k;
            if (r < LL) {
                zload(zptr(X, Y, a, r + 1), zn);
                #pragma unroll
                for (int p = 0; p < 4; ++p) { rowdz[k][p] = zn[p] - zp[p]; zp[p] = zn[p]; }
            } else {
                #pragma unroll
                for (int p = 0; p < 4; ++p) { rowdz[k][p].x = 0.0f; rowdz[k][p].y = 0.0f; }
            }
        }
    }

    for (int mi = mg; mi < MCH; mi += 4) {
        const int m  = m0 + mi;
        const int pm = m - t;
        const bool v0 = (unsigned)pm < 256u;   // col c0 = 2pm+1 valid
        const bool v1 = (unsigned)pm < 255u;   // col c1 = 2pm+2 valid

        // column dz's: j = 2pm (clamped for invalid lanes; values masked)
        int j = 2 * pm; j = j < 0 ? 0 : (j > 510 ? 510 : j);
        const int j2 = (j + 2 > 511) ? 511 : (j + 2);
        v2f za[4], zb[4], zc[4], c0[4], c1[4];
        zload(zptr(X, Y, a, j),     za);
        zload(zptr(X, Y, a, j + 1), zb);
        zload(zptr(X, Y, a, j2),    zc);
        #pragma unroll
        for (int p = 0; p < 4; ++p) { c0[p] = zb[p] - za[p]; c1[p] = zc[p] - zb[p]; }

        union { v4f q[4]; float f[16]; } eb;
        #pragma unroll
        for (int k = 0; k < 8; ++k) {
            v2f a0 = {-0.5f, -0.5f}, a1 = {-0.5f, -0.5f};
            #pragma unroll
            for (int p = 0; p < 4; ++p) {
                a0 += rowdz[k][p] * c0[p];
                a1 += rowdz[k][p] * c1[p];
            }
            eb.f[k]     = v0 ? (a0.x + a0.y) : 0.0f;   // <dz_r,dz_c0> - 1
            eb.f[8 + k] = v1 ? (a1.x + a1.y) : 0.0f;   // <dz_r,dz_c1> - 1
        }
        v4f* q = reinterpret_cast<v4f*>(E + (((size_t)a * MPAD + m) * 64 + t) * 16);
        q[0] = eb.q[0]; q[1] = eb.q[1]; q[2] = eb.q[2]; q[3] = eb.q[3];
    }
}

// ---------------- phase 2: the serial Goursat sweep --------------------------
union EBuf { v4f q[4]; float f[16]; };

#define LOADE(BUF, mf_)                                                       \
    { int mf = (mf_); mf = mf > (MPAD - 1) ? (MPAD - 1) : mf;                 \
      const v4f* qq = reinterpret_cast<const v4f*>(ep + (size_t)mf * 1024);   \
      BUF.q[0] = qq[0]; BUF.q[1] = qq[1]; BUF.q[2] = qq[2]; BUF.q[3] = qq[3]; }

#define PROC(BUF, m_)                                                         \
    { const int pm = (m_) - t;                                                \
      const bool v0 = (unsigned)pm < 256u;                                    \
      const bool v1 = (unsigned)pm < 255u;                                    \
      const float sb0 = wave_shr1(bot0, 1.0f);                                \
      const float sb1 = wave_shr1(bot1, 1.0f);                                \
      float up = sb0, diag = nb_prev;                                         \
      _Pragma("unroll")                                                       \
      for (int k = 0; k < 8; ++k) {                                           \
          const float nv = fmaf(diag, BUF.f[k], L[k]) + up;                   \
          diag = L[k]; L[k] = v0 ? nv : L[k]; up = nv;                        \
      }                                                                       \
      bot0 = L[7];                                                            \
      up = sb1; diag = sb0;                                                   \
      _Pragma("unroll")                                                       \
      for (int k = 0; k < 8; ++k) {                                           \
          const float nv = fmaf(diag, BUF.f[8 + k], L[k]) + up;               \
          diag = L[k]; L[k] = v1 ? nv : L[k]; up = nv;                        \
      }                                                                       \
      bot1 = L[7];                                                            \
      nb_prev = sb1; }

__global__ __launch_bounds__(64) void sweep_kernel(
        const float* __restrict__ E, float* __restrict__ out) {
    const int a = blockIdx.x;
    const int t = threadIdx.x;
    const float* ep = E + ((size_t)a * MPAD * 64 + t) * 16;

    EBuf Ab, Bb, Cb, Db;
    LOADE(Ab, 0); LOADE(Bb, 1); LOADE(Cb, 2); LOADE(Db, 3);

    float L[8];
    #pragma unroll
    for (int k = 0; k < 8; ++k) L[k] = 1.0f;
    float bot0 = 1.0f, bot1 = 1.0f, nb_prev = 1.0f;

    for (int m = 0; m < MPAD; m += 4) {
        PROC(Ab, m);     LOADE(Ab, m + 4);
        PROC(Bb, m + 1); LOADE(Bb, m + 5);
        PROC(Cb, m + 2); LOADE(Cb, m + 6);
        PROC(Db, m + 3); LOADE(Db, m + 7);
    }

    // K[511][511]: lane 63, grid row 511 = 8*63 + 6 + 1 -> L[6]
    if (t == 63) atomicAdd(out, sqrtf(L[6] - 1.0f) * (1.0f / (float)AA));
}

// ---------------- fallback (R4 monolithic kernel, proven) --------------------
__global__ __launch_bounds__(64) void sig_fallback_kernel(
        const float* __restrict__ X, const float* __restrict__ Y,
        float* __restrict__ out) {
    const int a = blockIdx.x;
    const int t = threadIdx.x;

    __shared__ __align__(16) float zbuf[NPTS][8];
    __shared__ __align__(16) v2f  dzc[NPTS][4];

    for (int p = t; p < NPTS; p += 64) {
        const float* src = zptr(X, Y, a, p);
        float4 v0 = reinterpret_cast<const float4*>(src)[0];
        float4 v1 = reinterpret_cast<const float4*>(src)[1];
        *reinterpret_cast<float4*>(&zbuf[p][0]) = v0;
        *reinterpret_cast<float4*>(&zbuf[p][4]) = v1;
    }
    __syncthreads();
    for (int i = t; i < NPTS; i += 64) {
        #pragma unroll
        for (int p = 0; p < 4; ++p) {
            v2f d;
            if (i < LL) {
                d.x = zbuf[i + 1][2 * p]     - zbuf[i][2 * p];
                d.y = zbuf[i + 1][2 * p + 1] - zbuf[i][2 * p + 1];
            } else { d.x = 0.0f; d.y = 0.0f; }
            dzc[i][p] = d;
        }
    }
    __syncthreads();

    v2f rowdz[8][4];
    #pragma unroll
    for (int k = 0; k < 8; ++k) {
        const int r = 8 * t + k;
        #pragma unroll
        for (int p = 0; p < 4; ++p) {
            v2f d;
            if (r < LL) {
                d.x = zbuf[r + 1][2 * p]     - zbuf[r][2 * p];
                d.y = zbuf[r + 1][2 * p + 1] - zbuf[r][2 * p + 1];
            } else { d.x = 0.0f; d.y = 0.0f; }
            rowdz[k][p] = d;
        }
    }

    float L[8];
    #pragma unroll
    for (int k = 0; k < 8; ++k) L[k] = 1.0f;
    float bot0 = 1.0f, bot1 = 1.0f, nb_prev = 1.0f;

    v2f ca[2][4], cb[2][4];
    #pragma unroll
    for (int p = 0; p < 4; ++p) {
        cb[0][p] = dzc[0][p]; cb[1][p] = dzc[1][p];
        ca[0][p] = cb[0][p];  ca[1][p] = cb[1][p];
    }
    for (int m = 0; m < 319; ++m) {
        const float sb0 = wave_shr1(bot0, 1.0f);
        const float sb1 = wave_shr1(bot1, 1.0f);
        #pragma unroll
        for (int p = 0; p < 4; ++p) {
            ca[0][p] = wave_shr1_v2(ca[0][p], cb[0][p]);
            ca[1][p] = wave_shr1_v2(ca[1][p], cb[1][p]);
        }
        {
            int jr = 2 * m + 2; jr = jr > 510 ? 510 : jr;
            #pragma unroll
            for (int p = 0; p < 4; ++p) { cb[0][p] = dzc[jr][p]; cb[1][p] = dzc[jr + 1][p]; }
        }
        const int um = m - t;
        const bool valid0 = (unsigned)um < 256u;
        const bool valid1 = (unsigned)um < 255u;
        {
            float up = sb0, diag = nb_prev;
            #pragma unroll
            for (int k = 0; k < 8; ++k) {
                v2f acc = {-0.5f, -0.5f};
                acc += rowdz[k][0] * ca[0][0];
                acc += rowdz[k][1] * ca[0][1];
                acc += rowdz[k][2] * ca[0][2];
                acc += rowdz[k][3] * ca[0][3];
                const float nv = fmaf(diag, acc.x + acc.y, L[k]) + up;
                diag = L[k];
                L[k] = valid0 ? nv : L[k];
                up = nv;
            }
            bot0 = L[7];
        }
        {
            float up = sb1, diag = sb0;
            #pragma unroll
            for (int k = 0; k < 8; ++k) {
                v2f acc = {-0.5f, -0.5f};
                acc += rowdz[k][0] * ca[1][0];
                acc += rowdz[k][1] * ca[1][1];
                acc += rowdz[k][2] * ca[1][2];
                acc += rowdz[k][3] * ca[1][3];
                const float nv = fmaf(diag, acc.x + acc.y, L[k]) + up;
                diag = L[k];
                L[k] = valid1 ? nv : L[k];
                up = nv;
            }
            bot1 = L[7];
        }
        nb_prev = sb1;
    }
    if (t == 63) atomicAdd(out, sqrtf(L[6] - 1.0f) * (1.0f / (float)AA));
}

extern "C" void kernel_launch(void* const* d_in, const int* in_sizes, int n_in,
                              void* d_out, int out_size, void* d_ws, size_t ws_size,
                              hipStream_t stream) {
    const float* X = (const float*)d_in[0];
    const float* Y = (const float*)d_in[1];
    float* out = (float*)d_out;
    const size_t need = (size_t)AA * MPAD * 64 * 16 * sizeof(float);  // 83.9 MB

    zero_out_kernel<<<1, 1, 0, stream>>>(out);
    if (ws_size >= need) {
        float* E = (float*)d_ws;
        gram2_kernel<<<dim3(AA, GBY), 256, 0, stream>>>(X, Y, E);
        sweep_kernel<<<AA, 64, 0, stream>>>(E, out);
    } else {
        sig_fallback_kernel<<<AA, 64, 0, stream>>>(X, Y, out);
    }
}

// Round 7
// 133.022 us; speedup vs baseline: 2.1659x; 1.2469x over previous
//
#include <hip/hip_runtime.h>
#include <math.h>

#define AA    64    // batch
#define SEQ   256   // per-path length
#define LL    511   // number of increments
#define NPTS  512   // padded dz rows
#define MPAD  320   // padded sweep iterations (319 real: 256 pairs + 63 skew)
#define MCH   8     // m-values per gram block (small => many blocks => TLP)
#define GBY   (MPAD / MCH)   // 40
#define DPTH  8     // sweep prefetch depth (8 slots x 4 loads = 32 in flight)

typedef float v2f __attribute__((ext_vector_type(2)));
typedef float v4f __attribute__((ext_vector_type(4)));

__global__ void zero_out_kernel(float* out) { out[0] = 0.0f; }

// Full-wave lane shift by 1 (DPP wave_shr:1, ctrl 0x138). Lane 0 <- `fill`.
__device__ __forceinline__ float wave_shr1(float x, float fill) {
    int r = __builtin_amdgcn_update_dpp(__float_as_int(fill), __float_as_int(x),
                                        0x138, 0xF, 0xF, false);
    return __int_as_float(r);
}
__device__ __forceinline__ v2f wave_shr1_v2(v2f x, v2f fill) {
    v2f r;
    r.x = wave_shr1(x.x, fill.x);
    r.y = wave_shr1(x.y, fill.y);
    return r;
}

// Z point p (0..511) of batch a: X rows then flipped Y rows.
__device__ __forceinline__ const float* zptr(const float* __restrict__ X,
                                             const float* __restrict__ Y,
                                             int a, int p) {
    return (p < SEQ) ? (X + ((size_t)a * SEQ + p) * 8)
                     : (Y + ((size_t)a * SEQ + (LL - p)) * 8);
}
__device__ __forceinline__ void zload(const float* p, v2f z[4]) {
    float4 u = reinterpret_cast<const float4*>(p)[0];
    float4 v = reinterpret_cast<const float4*>(p)[1];
    z[0].x = u.x; z[0].y = u.y; z[1].x = u.z; z[1].y = u.w;
    z[2].x = v.x; z[2].y = v.y; z[3].x = v.z; z[3].y = v.w;
}

// ---------------- phase 1: Gram values in sweep read-order -------------------
// Per iteration-block m (4096 B): layout [q:4][t:64][4 floats] so that every
// 16B-per-lane access (store here, load in sweep) is one contiguous 1KB
// wave transaction. Value semantics identical to the proven R6 gram2:
// f[k] = <dz[8t+k], dz[2(m-t)]+..> - 1 with q = idx>>2.
__global__ __launch_bounds__(256) void gram3_kernel(
        const float* __restrict__ X, const float* __restrict__ Y,
        float* __restrict__ E) {
    const int a  = blockIdx.x;
    const int m0 = blockIdx.y * MCH;
    const int t  = threadIdx.x & 63;
    const int mg = threadIdx.x >> 6;   // 0..3

    // this thread's 8 dz rows: dz[8t+k] = Z[8t+k+1] - Z[8t+k]; dz[511] = 0
    v2f rowdz[8][4];
    {
        v2f zp[4], zn[4];
        zload(zptr(X, Y, a, 8 * t), zp);
        #pragma unroll
        for (int k = 0; k < 8; ++k) {
            const int r = 8 * t + k;
            if (r < LL) {
                zload(zptr(X, Y, a, r + 1), zn);
                #pragma unroll
                for (int p = 0; p < 4; ++p) { rowdz[k][p] = zn[p] - zp[p]; zp[p] = zn[p]; }
            } else {
                #pragma unroll
                for (int p = 0; p < 4; ++p) { rowdz[k][p].x = 0.0f; rowdz[k][p].y = 0.0f; }
            }
        }
    }

    for (int mi = mg; mi < MCH; mi += 4) {
        const int m  = m0 + mi;
        const int pm = m - t;
        const bool v0 = (unsigned)pm < 256u;   // col c0 = 2pm+1 valid
        const bool v1 = (unsigned)pm < 255u;   // col c1 = 2pm+2 valid

        int j = 2 * pm; j = j < 0 ? 0 : (j > 510 ? 510 : j);
        const int j2 = (j + 2 > 511) ? 511 : (j + 2);
        v2f za[4], zb[4], zc[4], c0[4], c1[4];
        zload(zptr(X, Y, a, j),     za);
        zload(zptr(X, Y, a, j + 1), zb);
        zload(zptr(X, Y, a, j2),    zc);
        #pragma unroll
        for (int p = 0; p < 4; ++p) { c0[p] = zb[p] - za[p]; c1[p] = zc[p] - zb[p]; }

        union { v4f q[4]; float f[16]; } eb;
        #pragma unroll
        for (int k = 0; k < 8; ++k) {
            v2f a0 = {-0.5f, -0.5f}, a1 = {-0.5f, -0.5f};
            #pragma unroll
            for (int p = 0; p < 4; ++p) {
                a0 += rowdz[k][p] * c0[p];
                a1 += rowdz[k][p] * c1[p];
            }
            eb.f[k]     = v0 ? (a0.x + a0.y) : 0.0f;   // <dz_r,dz_c0> - 1
            eb.f[8 + k] = v1 ? (a1.x + a1.y) : 0.0f;   // <dz_r,dz_c1> - 1
        }
        // store: float index = (a*MPAD+m)*1024 + qi*256 + t*4
        float* bm = E + ((size_t)a * MPAD + m) * 1024;
        #pragma unroll
        for (int qi = 0; qi < 4; ++qi)
            *reinterpret_cast<v4f*>(bm + qi * 256 + t * 4) = eb.q[qi];
    }
}

// ---------------- phase 2: the serial Goursat sweep --------------------------
// 8-deep register-ring prefetch, pinned with volatile asm + counted vmcnt(28).
#define F0(S, k) (R[S][(k) >> 2][(k) & 3])
#define F1(S, k) (R[S][2 + ((k) >> 2)][(k) & 3])

#define ISSUE(S, mf_)                                                          \
    { int mf = (mf_); mf = mf > (MPAD - 1) ? (MPAD - 1) : mf;                  \
      const char* pp = ep + (size_t)mf * 4096;                                 \
      asm volatile("global_load_dwordx4 %0, %1, off"             : "=v"(R[S][0]) : "v"(pp)); \
      asm volatile("global_load_dwordx4 %0, %1, off offset:1024" : "=v"(R[S][1]) : "v"(pp)); \
      asm volatile("global_load_dwordx4 %0, %1, off offset:2048" : "=v"(R[S][2]) : "v"(pp)); \
      asm volatile("global_load_dwordx4 %0, %1, off offset:3072" : "=v"(R[S][3]) : "v"(pp)); }

// Wait until only 28 loads outstanding (= oldest slot's 4 landed). The "+v"
// ties make the slot's registers data-dependent on this asm, so no consumer
// can be scheduled above it.
#define WAITC(S)                                                               \
    asm volatile("s_waitcnt vmcnt(28)"                                         \
                 : "+v"(R[S][0]), "+v"(R[S][1]), "+v"(R[S][2]), "+v"(R[S][3]));

#define PROC(S, m_)                                                            \
    { const int pm = (m_) - t;                                                 \
      const bool v0 = (unsigned)pm < 256u;                                     \
      const bool v1 = (unsigned)pm < 255u;                                     \
      const float sb0 = wave_shr1(bot0, 1.0f);                                 \
      const float sb1 = wave_shr1(bot1, 1.0f);                                 \
      float up = sb0, diag = nb_prev;                                          \
      _Pragma("unroll")                                                        \
      for (int k = 0; k < 8; ++k) {                                            \
          const float nv = fmaf(diag, F0(S, k), L[k]) + up;                    \
          diag = L[k]; L[k] = v0 ? nv : L[k]; up = nv;                         \
      }                                                                        \
      bot0 = L[7];                                                             \
      up = sb1; diag = sb0;                                                    \
      _Pragma("unroll")                                                        \
      for (int k = 0; k < 8; ++k) {                                            \
          const float nv = fmaf(diag, F1(S, k), L[k]) + up;                    \
          diag = L[k]; L[k] = v1 ? nv : L[k]; up = nv;                         \
      }                                                                        \
      bot1 = L[7];                                                             \
      nb_prev = sb1; }

#define STEP(S, MM)  WAITC(S); PROC(S, MM); ISSUE(S, (MM) + DPTH);

__global__ __launch_bounds__(64) void sweep_kernel(
        const float* __restrict__ E, float* __restrict__ out) {
    const int a = blockIdx.x;
    const int t = threadIdx.x;
    // lane byte base: block m stride 4096B; within block q*1024 + t*16
    const char* ep = reinterpret_cast<const char*>(E)
                   + (size_t)a * MPAD * 4096 + (size_t)t * 16;

    v4f R[DPTH][4];   // all indices compile-time constant -> registers

    ISSUE(0, 0); ISSUE(1, 1); ISSUE(2, 2); ISSUE(3, 3);
    ISSUE(4, 4); ISSUE(5, 5); ISSUE(6, 6); ISSUE(7, 7);   // 32 in flight

    float L[8];
    #pragma unroll
    for (int k = 0; k < 8; ++k) L[k] = 1.0f;
    float bot0 = 1.0f, bot1 = 1.0f, nb_prev = 1.0f;

    for (int m = 0; m < MPAD; m += 8) {   // 320 = 40 x 8, exact
        STEP(0, m);     STEP(1, m + 1);  STEP(2, m + 2);  STEP(3, m + 3);
        STEP(4, m + 4); STEP(5, m + 5);  STEP(6, m + 6);  STEP(7, m + 7);
    }
    asm volatile("s_waitcnt vmcnt(0)");   // drain ring before endpgm

    // K[511][511]: lane 63, grid row 511 = 8*63 + 6 + 1 -> L[6]
    if (t == 63) atomicAdd(out, sqrtf(L[6] - 1.0f) * (1.0f / (float)AA));
}

// ---------------- fallback (R4 monolithic kernel, proven) --------------------
__global__ __launch_bounds__(64) void sig_fallback_kernel(
        const float* __restrict__ X, const float* __restrict__ Y,
        float* __restrict__ out) {
    const int a = blockIdx.x;
    const int t = threadIdx.x;

    __shared__ __align__(16) float zbuf[NPTS][8];
    __shared__ __align__(16) v2f  dzc[NPTS][4];

    for (int p = t; p < NPTS; p += 64) {
        const float* src = zptr(X, Y, a, p);
        float4 v0 = reinterpret_cast<const float4*>(src)[0];
        float4 v1 = reinterpret_cast<const float4*>(src)[1];
        *reinterpret_cast<float4*>(&zbuf[p][0]) = v0;
        *reinterpret_cast<float4*>(&zbuf[p][4]) = v1;
    }
    __syncthreads();
    for (int i = t; i < NPTS; i += 64) {
        #pragma unroll
        for (int p = 0; p < 4; ++p) {
            v2f d;
            if (i < LL) {
                d.x = zbuf[i + 1][2 * p]     - zbuf[i][2 * p];
                d.y = zbuf[i + 1][2 * p + 1] - zbuf[i][2 * p + 1];
            } else { d.x = 0.0f; d.y = 0.0f; }
            dzc[i][p] = d;
        }
    }
    __syncthreads();

    v2f rowdz[8][4];
    #pragma unroll
    for (int k = 0; k < 8; ++k) {
        const int r = 8 * t + k;
        #pragma unroll
        for (int p = 0; p < 4; ++p) {
            v2f d;
            if (r < LL) {
                d.x = zbuf[r + 1][2 * p]     - zbuf[r][2 * p];
                d.y = zbuf[r + 1][2 * p + 1] - zbuf[r][2 * p + 1];
            } else { d.x = 0.0f; d.y = 0.0f; }
            rowdz[k][p] = d;
        }
    }

    float L[8];
    #pragma unroll
    for (int k = 0; k < 8; ++k) L[k] = 1.0f;
    float bot0 = 1.0f, bot1 = 1.0f, nb_prev = 1.0f;

    v2f ca[2][4], cb[2][4];
    #pragma unroll
    for (int p = 0; p < 4; ++p) {
        cb[0][p] = dzc[0][p]; cb[1][p] = dzc[1][p];
        ca[0][p] = cb[0][p];  ca[1][p] = cb[1][p];
    }
    for (int m = 0; m < 319; ++m) {
        const float sb0 = wave_shr1(bot0, 1.0f);
        const float sb1 = wave_shr1(bot1, 1.0f);
        #pragma unroll
        for (int p = 0; p < 4; ++p) {
            ca[0][p] = wave_shr1_v2(ca[0][p], cb[0][p]);
            ca[1][p] = wave_shr1_v2(ca[1][p], cb[1][p]);
        }
        {
            int jr = 2 * m + 2; jr = jr > 510 ? 510 : jr;
            #pragma unroll
            for (int p = 0; p < 4; ++p) { cb[0][p] = dzc[jr][p]; cb[1][p] = dzc[jr + 1][p]; }
        }
        const int um = m - t;
        const bool valid0 = (unsigned)um < 256u;
        const bool valid1 = (unsigned)um < 255u;
        {
            float up = sb0, diag = nb_prev;
            #pragma unroll
            for (int k = 0; k < 8; ++k) {
                v2f acc = {-0.5f, -0.5f};
                acc += rowdz[k][0] * ca[0][0];
                acc += rowdz[k][1] * ca[0][1];
                acc += rowdz[k][2] * ca[0][2];
                acc += rowdz[k][3] * ca[0][3];
                const float nv = fmaf(diag, acc.x + acc.y, L[k]) + up;
                diag = L[k];
                L[k] = valid0 ? nv : L[k];
                up = nv;
            }
            bot0 = L[7];
        }
        {
            float up = sb1, diag = sb0;
            #pragma unroll
            for (int k = 0; k < 8; ++k) {
                v2f acc = {-0.5f, -0.5f};
                acc += rowdz[k][0] * ca[1][0];
                acc += rowdz[k][1] * ca[1][1];
                acc += rowdz[k][2] * ca[1][2];
                acc += rowdz[k][3] * ca[1][3];
                const float nv = fmaf(diag, acc.x + acc.y, L[k]) + up;
                diag = L[k];
                L[k] = valid1 ? nv : L[k];
                up = nv;
            }
            bot1 = L[7];
        }
        nb_prev = sb1;
    }
    if (t == 63) atomicAdd(out, sqrtf(L[6] - 1.0f) * (1.0f / (float)AA));
}

extern "C" void kernel_launch(void* const* d_in, const int* in_sizes, int n_in,
                              void* d_out, int out_size, void* d_ws, size_t ws_size,
                              hipStream_t stream) {
    const float* X = (const float*)d_in[0];
    const float* Y = (const float*)d_in[1];
    float* out = (float*)d_out;
    const size_t need = (size_t)AA * MPAD * 4096;  // 83.9 MB

    zero_out_kernel<<<1, 1, 0, stream>>>(out);
    if (ws_size >= need) {
        float* E = (float*)d_ws;
        gram3_kernel<<<dim3(AA, GBY), 256, 0, stream>>>(X, Y, E);
        sweep_kernel<<<AA, 64, 0, stream>>>(E, out);
    } else {
        sig_fallback_kernel<<<AA, 64, 0, stream>>>(X, Y, out);
    }
}

// Round 8
// 107.581 us; speedup vs baseline: 2.6781x; 1.2365x over previous
//
#include <hip/hip_runtime.h>
#include <math.h>

#define AA    64    // batch
#define SEQ   256   // per-path length
#define LL    511   // number of increments
#define MPAD  320   // padded sweep iterations (319 real: 256 pairs + 63 skew)
#define CH    6     // m-iterations per chunk
#define NCHK  54    // 54*6 = 324 >= MPAD (tail masked)

typedef float v2f __attribute__((ext_vector_type(2)));
typedef float v4f __attribute__((ext_vector_type(4)));

__global__ void zero_out_kernel(float* out) { out[0] = 0.0f; }

// Full-wave lane shift by 1 (DPP wave_shr:1, ctrl 0x138). Lane 0 <- `fill`.
__device__ __forceinline__ float wave_shr1(float x, float fill) {
    int r = __builtin_amdgcn_update_dpp(__float_as_int(fill), __float_as_int(x),
                                        0x138, 0xF, 0xF, false);
    return __int_as_float(r);
}

// Z point p (0..511) of batch a: X rows then flipped Y rows.
__device__ __forceinline__ const float* zptr(const float* __restrict__ X,
                                             const float* __restrict__ Y,
                                             int a, int p) {
    return (p < SEQ) ? (X + ((size_t)a * SEQ + p) * 8)
                     : (Y + ((size_t)a * SEQ + (LL - p)) * 8);
}
__device__ __forceinline__ void zload(const float* p, v2f z[4]) {
    float4 u = reinterpret_cast<const float4*>(p)[0];
    float4 v = reinterpret_cast<const float4*>(p)[1];
    z[0].x = u.x; z[0].y = u.y; z[1].x = u.z; z[1].y = u.w;
    z[2].x = v.x; z[2].y = v.y; z[3].x = v.z; z[3].y = v.w;
}

// Produce one m-iteration of E into LDS (value math identical to the proven
// R7 gram3): f[k] = <dz[8t+k], dz[2(m-t)]> - 1, f[8+k] = <dz[8t+k],
// dz[2(m-t)+1]> - 1, zeros when the (m,t) pair is out of range. Layout per
// m-slot: float offset qi*256 + t*4 (byte qi*1024 + t*16), matching the
// proven R7 sweep fragment mapping.
__device__ __forceinline__ void produce_m(
        const float* __restrict__ X, const float* __restrict__ Y,
        int a, int t, int m, const v2f rowdz[8][4], float* __restrict__ ebase) {
    const int pm = m - t;
    const bool v0 = (unsigned)pm < 256u;   // grid col 2pm+1 valid
    const bool v1 = (unsigned)pm < 255u;   // grid col 2pm+2 valid

    int j = 2 * pm; j = j < 0 ? 0 : (j > 510 ? 510 : j);
    const int j2 = (j + 2 > 511) ? 511 : (j + 2);
    v2f za[4], zb[4], zc[4], c0[4], c1[4];
    zload(zptr(X, Y, a, j),     za);
    zload(zptr(X, Y, a, j + 1), zb);
    zload(zptr(X, Y, a, j2),    zc);
    #pragma unroll
    for (int p = 0; p < 4; ++p) { c0[p] = zb[p] - za[p]; c1[p] = zc[p] - zb[p]; }

    union { v4f q[4]; float f[16]; } eb;
    #pragma unroll
    for (int k = 0; k < 8; ++k) {
        v2f a0 = {-0.5f, -0.5f}, a1 = {-0.5f, -0.5f};
        #pragma unroll
        for (int p = 0; p < 4; ++p) {
            a0 += rowdz[k][p] * c0[p];
            a1 += rowdz[k][p] * c1[p];
        }
        eb.f[k]     = v0 ? (a0.x + a0.y) : 0.0f;
        eb.f[8 + k] = v1 ? (a1.x + a1.y) : 0.0f;
    }
    #pragma unroll
    for (int qi = 0; qi < 4; ++qi)
        *reinterpret_cast<v4f*>(ebase + qi * 256 + t * 4) = eb.q[qi];
}

// Proven R7 sweep step (store-masked), fed from Rg fragments.
#define F0(MI, k) (Rg[MI][(k) >> 2][(k) & 3])
#define F1(MI, k) (Rg[MI][2 + ((k) >> 2)][(k) & 3])
#define PROCM(MI, m_)                                                          \
    { const int pm = (m_) - t;                                                 \
      const bool v0 = (unsigned)pm < 256u;                                     \
      const bool v1 = (unsigned)pm < 255u;                                     \
      const float sb0 = wave_shr1(bot0, 1.0f);                                 \
      const float sb1 = wave_shr1(bot1, 1.0f);                                 \
      float up = sb0, diag = nb_prev;                                          \
      _Pragma("unroll")                                                        \
      for (int k = 0; k < 8; ++k) {                                            \
          const float nv = fmaf(diag, F0(MI, k), L[k]) + up;                   \
          diag = L[k]; L[k] = v0 ? nv : L[k]; up = nv;                         \
      }                                                                        \
      bot0 = L[7];                                                             \
      up = sb1; diag = sb0;                                                    \
      _Pragma("unroll")                                                        \
      for (int k = 0; k < 8; ++k) {                                            \
          const float nv = fmaf(diag, F1(MI, k), L[k]) + up;                   \
          diag = L[k]; L[k] = v1 ? nv : L[k]; up = nv;                         \
      }                                                                        \
      bot1 = L[7];                                                             \
      nb_prev = sb1; }

// One block per batch element. Waves 0..5 produce chunk c+1 into
// Ebuf[(c+1)&1] while wave 6 sweeps chunk c from Ebuf[c&1]; one
// __syncthreads per chunk. E never leaves LDS.
__global__ __launch_bounds__(448) void fused_kernel(
        const float* __restrict__ X, const float* __restrict__ Y,
        float* __restrict__ out) {
    const int a  = blockIdx.x;
    const int wv = threadIdx.x >> 6;   // 0..5 producers, 6 sweeper
    const int t  = threadIdx.x & 63;

    __shared__ __align__(16) float Ebuf[2][CH][1024];   // 48 KB

    // ---- producer persistent state: this lane's 8 dz rows (L1-resident Z) ----
    v2f rowdz[8][4];
    if (wv < CH) {
        v2f zp[4], zn[4];
        zload(zptr(X, Y, a, 8 * t), zp);
        #pragma unroll
        for (int k = 0; k < 8; ++k) {
            const int r = 8 * t + k;
            if (r < LL) {
                zload(zptr(X, Y, a, r + 1), zn);
                #pragma unroll
                for (int p = 0; p < 4; ++p) { rowdz[k][p] = zn[p] - zp[p]; zp[p] = zn[p]; }
            } else {
                #pragma unroll
                for (int p = 0; p < 4; ++p) { rowdz[k][p].x = 0.0f; rowdz[k][p].y = 0.0f; }
            }
        }
        // prologue: produce chunk 0 (m = wv)
        produce_m(X, Y, a, t, wv, rowdz, &Ebuf[0][wv][0]);
    }

    // ---- sweeper persistent state ----
    float L[8];
    #pragma unroll
    for (int k = 0; k < 8; ++k) L[k] = 1.0f;
    float bot0 = 1.0f, bot1 = 1.0f, nb_prev = 1.0f;

    __syncthreads();

    for (int c = 0; c < NCHK; ++c) {
        if (wv < CH) {
            const int cc = c + 1;
            if (cc < NCHK)
                produce_m(X, Y, a, t, cc * CH + wv, rowdz, &Ebuf[cc & 1][wv][0]);
        } else {
            // consume chunk c: 24 ds_read_b128 into regs, then 6 PROC steps
            const float* bp = &Ebuf[c & 1][0][0] + t * 4;
            v4f Rg[CH][4];
            #pragma unroll
            for (int mi = 0; mi < CH; ++mi)
                #pragma unroll
                for (int qi = 0; qi < 4; ++qi)
                    Rg[mi][qi] = *reinterpret_cast<const v4f*>(bp + mi * 1024 + qi * 256);
            const int mb = c * CH;
            PROCM(0, mb);     PROCM(1, mb + 1); PROCM(2, mb + 2);
            PROCM(3, mb + 3); PROCM(4, mb + 4); PROCM(5, mb + 5);
        }
        __syncthreads();
    }

    // K[511][511]: sweeper lane 63, grid row 511 = 8*63 + 6 + 1 -> L[6]
    if (wv == CH && t == 63)
        atomicAdd(out, sqrtf(L[6] - 1.0f) * (1.0f / (float)AA));
}

extern "C" void kernel_launch(void* const* d_in, const int* in_sizes, int n_in,
                              void* d_out, int out_size, void* d_ws, size_t ws_size,
                              hipStream_t stream) {
    const float* X = (const float*)d_in[0];
    const float* Y = (const float*)d_in[1];
    float* out = (float*)d_out;

    zero_out_kernel<<<1, 1, 0, stream>>>(out);
    fused_kernel<<<AA, 448, 0, stream>>>(X, Y, out);
}

// Round 9
// 105.058 us; speedup vs baseline: 2.7424x; 1.0240x over previous
//
#include <hip/hip_runtime.h>
#include <math.h>

#define AA    64    // batch
#define SEQ   256   // per-path length
#define LL    511   // number of increments
#define MPAD  320   // padded sweep iterations (319 real: 256 pairs + 63 skew)
#define CH    6     // m-iterations per chunk
#define NCHK  54    // 54*6 = 324 >= MPAD (tail masked)

typedef float v2f __attribute__((ext_vector_type(2)));
typedef float v4f __attribute__((ext_vector_type(4)));

__global__ void zero_out_kernel(float* out) { out[0] = 0.0f; }

// Full-wave lane shift by 1 (DPP wave_shr:1, ctrl 0x138). Lane 0 <- `fill`.
__device__ __forceinline__ float wave_shr1(float x, float fill) {
    int r = __builtin_amdgcn_update_dpp(__float_as_int(fill), __float_as_int(x),
                                        0x138, 0xF, 0xF, false);
    return __int_as_float(r);
}

// Z point p (0..511) of batch a: X rows then flipped Y rows.
__device__ __forceinline__ const float* zptr(const float* __restrict__ X,
                                             const float* __restrict__ Y,
                                             int a, int p) {
    return (p < SEQ) ? (X + ((size_t)a * SEQ + p) * 8)
                     : (Y + ((size_t)a * SEQ + (LL - p)) * 8);
}
__device__ __forceinline__ void zload(const float* p, v2f z[4]) {
    float4 u = reinterpret_cast<const float4*>(p)[0];
    float4 v = reinterpret_cast<const float4*>(p)[1];
    z[0].x = u.x; z[0].y = u.y; z[1].x = u.z; z[1].y = u.w;
    z[2].x = v.x; z[2].y = v.y; z[3].x = v.z; z[3].y = v.w;
}

// Produce one m-iteration of E into LDS. Value math identical to the proven
// R8 produce_m (gram3 semantics): f[k] = <dz[8t+k], dz[2(m-t)]> - 1,
// f[8+k] = <dz[8t+k], dz[2(m-t)+1]> - 1, zeros when (m,t) out of range.
// Column dz now comes from the parity-split LDS table (8B lane stride,
// conflict-free) instead of 64B-strided global loads.
__device__ __forceinline__ void produce_m_lds(
        int t, int m, const v2f rowdz[8][4], const v2f (*dzs)[2][256],
        float* __restrict__ ebase) {
    const int pm0 = m - t;
    const bool v0 = (unsigned)pm0 < 256u;   // grid col 2pm+1 valid
    const bool v1 = (unsigned)pm0 < 255u;   // grid col 2pm+2 valid
    const int pm = pm0 < 0 ? 0 : (pm0 > 255 ? 255 : pm0);

    v2f c0[4], c1[4];
    #pragma unroll
    for (int p = 0; p < 4; ++p) {
        c0[p] = dzs[p][0][pm];   // dz[2pm]   (even plane)
        c1[p] = dzs[p][1][pm];   // dz[2pm+1] (odd plane; [1][255] = dz[511] = 0)
    }

    union { v4f q[4]; float f[16]; } eb;
    #pragma unroll
    for (int k = 0; k < 8; ++k) {
        v2f a0 = {-0.5f, -0.5f}, a1 = {-0.5f, -0.5f};
        #pragma unroll
        for (int p = 0; p < 4; ++p) {
            a0 += rowdz[k][p] * c0[p];
            a1 += rowdz[k][p] * c1[p];
        }
        eb.f[k]     = v0 ? (a0.x + a0.y) : 0.0f;
        eb.f[8 + k] = v1 ? (a1.x + a1.y) : 0.0f;
    }
    #pragma unroll
    for (int qi = 0; qi < 4; ++qi)
        *reinterpret_cast<v4f*>(ebase + qi * 256 + t * 4) = eb.q[qi];
}

// Proven R8 sweep step (store-masked), fed from Rg fragments.
#define F0(MI, k) (Rg[MI][(k) >> 2][(k) & 3])
#define F1(MI, k) (Rg[MI][2 + ((k) >> 2)][(k) & 3])
#define PROCM(MI, m_)                                                          \
    { const int pm = (m_) - t;                                                 \
      const bool v0 = (unsigned)pm < 256u;                                     \
      const bool v1 = (unsigned)pm < 255u;                                     \
      const float sb0 = wave_shr1(bot0, 1.0f);                                 \
      const float sb1 = wave_shr1(bot1, 1.0f);                                 \
      float up = sb0, diag = nb_prev;                                          \
      _Pragma("unroll")                                                        \
      for (int k = 0; k < 8; ++k) {                                            \
          const float nv = fmaf(diag, F0(MI, k), L[k]) + up;                   \
          diag = L[k]; L[k] = v0 ? nv : L[k]; up = nv;                         \
      }                                                                        \
      bot0 = L[7];                                                             \
      up = sb1; diag = sb0;                                                    \
      _Pragma("unroll")                                                        \
      for (int k = 0; k < 8; ++k) {                                            \
          const float nv = fmaf(diag, F1(MI, k), L[k]) + up;                   \
          diag = L[k]; L[k] = v1 ? nv : L[k]; up = nv;                         \
      }                                                                        \
      bot1 = L[7];                                                             \
      nb_prev = sb1; }

// One block per batch element. Waves 0..5 produce chunk c+1 into
// Ebuf[(c+1)&1] while wave 6 sweeps chunk c from Ebuf[c&1]; one
// __syncthreads per chunk. E and dz never leave LDS after staging.
__global__ __launch_bounds__(448) void fused_kernel(
        const float* __restrict__ X, const float* __restrict__ Y,
        float* __restrict__ out) {
    const int a  = blockIdx.x;
    const int wv = threadIdx.x >> 6;   // 0..5 producers, 6 sweeper
    const int t  = threadIdx.x & 63;

    __shared__ __align__(16) float Ebuf[2][CH][1024];    // 48 KB
    __shared__ __align__(16) v2f  dzs[4][2][256];        // 16 KB: [pair][j&1][j>>1]

    // ---- stage dz into LDS (one pass over 512 columns; dz[511] = 0) ----
    for (int i = threadIdx.x; i < 512; i += 448) {
        v2f d[4];
        if (i < LL) {
            v2f za[4], zb[4];
            zload(zptr(X, Y, a, i),     za);
            zload(zptr(X, Y, a, i + 1), zb);
            #pragma unroll
            for (int p = 0; p < 4; ++p) d[p] = zb[p] - za[p];
        } else {
            #pragma unroll
            for (int p = 0; p < 4; ++p) { d[p].x = 0.0f; d[p].y = 0.0f; }
        }
        #pragma unroll
        for (int p = 0; p < 4; ++p) dzs[p][i & 1][i >> 1] = d[p];
    }
    __syncthreads();

    // ---- producer persistent state: this lane's 8 dz rows (from LDS) ----
    v2f rowdz[8][4];
    if (wv < CH) {
        #pragma unroll
        for (int k = 0; k < 8; ++k) {
            const int r = 8 * t + k;
            #pragma unroll
            for (int p = 0; p < 4; ++p) rowdz[k][p] = dzs[p][r & 1][r >> 1];
        }
        // prologue: produce chunk 0 (m = wv)
        produce_m_lds(t, wv, rowdz, dzs, &Ebuf[0][wv][0]);
    }

    // ---- sweeper persistent state ----
    float L[8];
    #pragma unroll
    for (int k = 0; k < 8; ++k) L[k] = 1.0f;
    float bot0 = 1.0f, bot1 = 1.0f, nb_prev = 1.0f;

    __syncthreads();

    for (int c = 0; c < NCHK; ++c) {
        if (wv < CH) {
            const int cc = c + 1;
            if (cc < NCHK)
                produce_m_lds(t, cc * CH + wv, rowdz, dzs, &Ebuf[cc & 1][wv][0]);
        } else {
            // consume chunk c: 24 ds_read_b128 into regs, then 6 PROC steps
            const float* bp = &Ebuf[c & 1][0][0] + t * 4;
            v4f Rg[CH][4];
            #pragma unroll
            for (int mi = 0; mi < CH; ++mi)
                #pragma unroll
                for (int qi = 0; qi < 4; ++qi)
                    Rg[mi][qi] = *reinterpret_cast<const v4f*>(bp + mi * 1024 + qi * 256);
            const int mb = c * CH;
            PROCM(0, mb);     PROCM(1, mb + 1); PROCM(2, mb + 2);
            PROCM(3, mb + 3); PROCM(4, mb + 4); PROCM(5, mb + 5);
        }
        __syncthreads();
    }

    // K[511][511]: sweeper lane 63, grid row 511 = 8*63 + 6 + 1 -> L[6]
    if (wv == CH && t == 63)
        atomicAdd(out, sqrtf(L[6] - 1.0f) * (1.0f / (float)AA));
}

extern "C" void kernel_launch(void* const* d_in, const int* in_sizes, int n_in,
                              void* d_out, int out_size, void* d_ws, size_t ws_size,
                              hipStream_t stream) {
    const float* X = (const float*)d_in[0];
    const float* Y = (const float*)d_in[1];
    float* out = (float*)d_out;

    zero_out_kernel<<<1, 1, 0, stream>>>(out);
    fused_kernel<<<AA, 448, 0, stream>>>(X, Y, out);
}